// Round 1
// baseline (390.697 us; speedup 1.0000x reference)
//
#include <hip/hip_runtime.h>

constexpr int NF = 169;   // flat feature count / fc2 out
constexpr int NP = 36;    // pooled features (6x6)
constexpr int NH = 128;   // hidden

__global__ __launch_bounds__(256) void fused_net(
    const float* __restrict__ x,
    const float* __restrict__ w1,
    const float* __restrict__ b1,
    const float* __restrict__ w2,
    const float* __restrict__ b2,
    float* __restrict__ out)
{
    __shared__ float w1s[NH * NP];   // 18.4 KB
    __shared__ float w2s[NF * NH];   // 86.5 KB
    __shared__ float b1s[NH];
    __shared__ float b2s[NF];

    const int tid = threadIdx.x;
    for (int i = tid; i < NH * NP; i += 256) w1s[i] = w1[i];
    for (int i = tid; i < NF * NH; i += 256) w2s[i] = w2[i];
    if (tid < NH) b1s[tid] = b1[tid];
    if (tid < NF) b2s[tid] = b2[tid];
    __syncthreads();

    const long row = (long)blockIdx.x * 256 + tid;
    const float* __restrict__ xr = x + row * NF;

    // ---- avg-pool 3x3 stride 2 over 14x14 zero-padded grid, /9, then relu ----
    float pooled[NP];
    #pragma unroll
    for (int i = 0; i < 6; ++i) {
        float g[3][14];
        #pragma unroll
        for (int rr = 0; rr < 3; ++rr) {
            #pragma unroll
            for (int c = 0; c < 14; ++c) {
                const int idx = (2 * i + rr) * 14 + c;   // compile-time constant
                g[rr][c] = (idx < NF) ? xr[idx] : 0.0f;  // pad region folds to 0
            }
        }
        #pragma unroll
        for (int j = 0; j < 6; ++j) {
            float s = 0.0f;
            #pragma unroll
            for (int rr = 0; rr < 3; ++rr)
                #pragma unroll
                for (int cc = 0; cc < 3; ++cc)
                    s += g[rr][2 * j + cc];
            pooled[i * 6 + j] = fmaxf(s * (1.0f / 9.0f), 0.0f);
        }
    }

    // ---- fc1 (36 -> 128) + relu ----
    float h[NH];
    #pragma unroll 4
    for (int j = 0; j < NH; ++j) {
        float acc = b1s[j];
        #pragma unroll
        for (int k = 0; k < NP; ++k)
            acc = fmaf(pooled[k], w1s[j * NP + k], acc);
        h[j] = fmaxf(acc, 0.0f);
    }

    // ---- fc2 (128 -> 169) ----
    float* __restrict__ orow = out + row * NF;
    #pragma unroll 1
    for (int o = 0; o < NF; ++o) {
        float acc = b2s[o];
        #pragma unroll
        for (int k = 0; k < NH; ++k)
            acc = fmaf(h[k], w2s[o * NH + k], acc);
        orow[o] = acc;
    }
}

extern "C" void kernel_launch(void* const* d_in, const int* in_sizes, int n_in,
                              void* d_out, int out_size, void* d_ws, size_t ws_size,
                              hipStream_t stream) {
    const float* x  = (const float*)d_in[0];
    const float* w1 = (const float*)d_in[1];
    const float* b1 = (const float*)d_in[2];
    const float* w2 = (const float*)d_in[3];
    const float* b2 = (const float*)d_in[4];
    float* out = (float*)d_out;

    const int rows = in_sizes[0] / NF;          // 131072
    const int blocks = (rows + 255) / 256;      // 512
    fused_net<<<blocks, 256, 0, stream>>>(x, w1, b1, w2, b2, out);
}

// Round 2
// 108.044 us; speedup vs baseline: 3.6161x; 3.6161x over previous
//
#include <hip/hip_runtime.h>
#include <hip/hip_bf16.h>

typedef __attribute__((ext_vector_type(8))) short short8;
typedef __attribute__((ext_vector_type(4))) float f32x4;

constexpr int NF = 169;   // in features / out features
constexpr int NH = 128;   // hidden
constexpr int NP = 36;    // pooled (6x6)
constexpr int KP = 64;    // padded K for gemm1
constexpr int W1_LD = 72; // w1s row stride (bf16 elems): 64 + 8 pad
constexpr int PL_LD = 72; // pooled row stride
constexpr int H_LD  = 136;// h row stride: 128 + 8 pad
constexpr int W2_LD = 136;// w2s row stride
constexpr int NO = 176;   // out features padded to 11*16

#define MFMA(a, b, c) __builtin_amdgcn_mfma_f32_16x16x32_bf16(a, b, c, 0, 0, 0)

__device__ inline unsigned short f2bf(float f) {
    __hip_bfloat16 h = __float2bfloat16(f);
    return *reinterpret_cast<unsigned short*>(&h);
}

__global__ __launch_bounds__(256) void fused_net_mfma(
    const float* __restrict__ x,
    const float* __restrict__ w1,
    const float* __restrict__ b1,
    const float* __restrict__ w2,
    const float* __restrict__ b2,
    float* __restrict__ out)
{
    __shared__ unsigned short w1s[NH][W1_LD];        // 18432 B
    __shared__ unsigned short w2s[NO][W2_LD];        // 47872 B
    __shared__ unsigned short pool_s[4][64][PL_LD];  // 36864 B
    __shared__ unsigned short h_s[4][16][H_LD];      // 17408 B
    __shared__ float b1s[NH];                        // 512 B
    __shared__ float b2s[NO];                        // 704 B

    const int tid = threadIdx.x;

    // ---- stage weights (bf16) ----
    for (int i = tid; i < NH * KP; i += 256) {
        int n = i / KP, k = i % KP;
        w1s[n][k] = f2bf(k < NP ? w1[n * NP + k] : 0.0f);
    }
    for (int i = tid; i < NO * NH; i += 256) {
        int o = i / NH, k = i % NH;
        w2s[o][k] = f2bf(o < NF ? w2[o * NH + k] : 0.0f);
    }
    if (tid < NH) b1s[tid] = b1[tid];
    if (tid < NO) b2s[tid] = (tid < NF) ? b2[tid] : 0.0f;

    // ---- per-thread pooling (row = blockRow + tid) ----
    const long row = (long)blockIdx.x * 256 + tid;
    const float* __restrict__ xr = x + row * NF;

    float pooled[NP];
    #pragma unroll
    for (int i = 0; i < 6; ++i) {
        float g[3][14];
        #pragma unroll
        for (int rr = 0; rr < 3; ++rr) {
            #pragma unroll
            for (int c = 0; c < 14; ++c) {
                const int idx = (2 * i + rr) * 14 + c;
                g[rr][c] = (idx < NF) ? xr[idx] : 0.0f;
            }
        }
        #pragma unroll
        for (int j = 0; j < 6; ++j) {
            float s = 0.0f;
            #pragma unroll
            for (int rr = 0; rr < 3; ++rr)
                #pragma unroll
                for (int cc = 0; cc < 3; ++cc)
                    s += g[rr][2 * j + cc];
            pooled[i * 6 + j] = fmaxf(s * (1.0f / 9.0f), 0.0f);
        }
    }

    const int wid  = tid >> 6;
    const int lane = tid & 63;

    // write pooled row as bf16, k in [0,36) data, [36,64) zeros
    {
        unsigned int* prow = (unsigned int*)&pool_s[wid][lane][0];
        #pragma unroll
        for (int i = 0; i < 18; ++i) {
            unsigned int lo = f2bf(pooled[2 * i]);
            unsigned int hi = f2bf(pooled[2 * i + 1]);
            prow[i] = lo | (hi << 16);
        }
        #pragma unroll
        for (int i = 18; i < 32; ++i) prow[i] = 0;
    }
    __syncthreads();

    // ---- per-wave MFMA over 4 m-tiles (wave owns rows 64*wid .. +63) ----
    const int lane_r  = lane & 15;   // fragment row/col index
    const int lane_hi = lane >> 4;   // 0..3

    const long out_row_base = (long)blockIdx.x * 256 + wid * 64;

    for (int mt = 0; mt < 4; ++mt) {
        // GEMM1: A = pooled[16 x 64], B = w1c[64 x 128] -> h tile [16 x 128]
        short8 a0 = *reinterpret_cast<const short8*>(
            &pool_s[wid][mt * 16 + lane_r][0 * 32 + lane_hi * 8]);
        short8 a1 = *reinterpret_cast<const short8*>(
            &pool_s[wid][mt * 16 + lane_r][1 * 32 + lane_hi * 8]);

        f32x4 acc1[8];
        #pragma unroll
        for (int nt = 0; nt < 8; ++nt) {
            short8 b0 = *reinterpret_cast<const short8*>(
                &w1s[nt * 16 + lane_r][0 * 32 + lane_hi * 8]);
            short8 b1f = *reinterpret_cast<const short8*>(
                &w1s[nt * 16 + lane_r][1 * 32 + lane_hi * 8]);
            f32x4 c = {0.f, 0.f, 0.f, 0.f};
            c = MFMA(a0, b0, c);
            c = MFMA(a1, b1f, c);
            acc1[nt] = c;
        }

        // bias + relu + bf16, write h tile to LDS (transpose for A2-frag)
        #pragma unroll
        for (int nt = 0; nt < 8; ++nt) {
            float bias = b1s[nt * 16 + lane_r];
            #pragma unroll
            for (int r = 0; r < 4; ++r) {
                float v = fmaxf(acc1[nt][r] + bias, 0.0f);
                h_s[wid][lane_hi * 4 + r][nt * 16 + lane_r] = f2bf(v);
            }
        }
        __syncthreads();

        // GEMM2: A = h[16 x 128], B = w2c[128 x 176]
        short8 a2[4];
        #pragma unroll
        for (int ks = 0; ks < 4; ++ks)
            a2[ks] = *reinterpret_cast<const short8*>(
                &h_s[wid][lane_r][ks * 32 + lane_hi * 8]);

        #pragma unroll
        for (int ot = 0; ot < 11; ++ot) {
            f32x4 acc = {0.f, 0.f, 0.f, 0.f};
            #pragma unroll
            for (int ks = 0; ks < 4; ++ks) {
                short8 bf = *reinterpret_cast<const short8*>(
                    &w2s[ot * 16 + lane_r][ks * 32 + lane_hi * 8]);
                acc = MFMA(a2[ks], bf, acc);
            }
            const int o = ot * 16 + lane_r;
            if (o < NF) {
                const float bias = b2s[o];
                #pragma unroll
                for (int r = 0; r < 4; ++r) {
                    const long grow = out_row_base + mt * 16 + lane_hi * 4 + r;
                    out[grow * NF + o] = acc[r] + bias;
                }
            }
        }
        __syncthreads();
    }
}

extern "C" void kernel_launch(void* const* d_in, const int* in_sizes, int n_in,
                              void* d_out, int out_size, void* d_ws, size_t ws_size,
                              hipStream_t stream) {
    const float* x  = (const float*)d_in[0];
    const float* w1 = (const float*)d_in[1];
    const float* b1 = (const float*)d_in[2];
    const float* w2 = (const float*)d_in[3];
    const float* b2 = (const float*)d_in[4];
    float* out = (float*)d_out;

    const int rows = in_sizes[0] / NF;      // 131072
    const int blocks = rows / 256;          // 512
    fused_net_mfma<<<blocks, 256, 0, stream>>>(x, w1, b1, w2, b2, out);
}

// Round 3
// 40.954 us; speedup vs baseline: 9.5399x; 2.6382x over previous
//
#include <hip/hip_runtime.h>
#include <hip/hip_bf16.h>

typedef __attribute__((ext_vector_type(8))) short short8;
typedef __attribute__((ext_vector_type(4))) float f32x4;
typedef float f4a __attribute__((ext_vector_type(4), aligned(4)));  // align-4 float4

constexpr int NF = 169;
constexpr int NH = 128;

#define MFMA(a, b, c) __builtin_amdgcn_mfma_f32_16x16x32_bf16(a, b, c, 0, 0, 0)

__device__ inline unsigned short f2bf(float f) {
    union { __hip_bfloat16 h; unsigned short u; } c;
    c.h = __float2bfloat16(f);
    return c.u;
}

// LDS map (78336 B total, 16B aligned):
//  [0, 65536):      pool_g[8][256][8] bf16 (32768 B)  --later aliased by--> h_g[16][256][8] bf16
//  [65536, 77824):  w1g[8][128][8] bf16 (12288 B)     --later aliased by--> stage[16][169] f32 (10816 B)
//  [77824, 78336):  b1s[128] f32
__global__ __launch_bounds__(256, 2) void fused_v3(
    const float* __restrict__ x,
    const float* __restrict__ w1,
    const float* __restrict__ b1,
    const float* __restrict__ w2,
    const float* __restrict__ b2,
    float* __restrict__ out)
{
    __shared__ __align__(16) char smem[78336];
    unsigned short* pool_g = (unsigned short*)smem;            // [8][256][8]
    unsigned short* h_g    = (unsigned short*)smem;            // [16][256][8]
    unsigned short* w1g    = (unsigned short*)(smem + 65536);  // [8][128][8]
    float*          stage  = (float*)(smem + 65536);           // [16][169]
    float*          b1s    = (float*)(smem + 77824);           // [128]

    const int tid  = threadIdx.x;
    const int wid  = tid >> 6;
    const int lane = tid & 63;
    const int lr   = lane & 15;
    const int hi   = lane >> 4;

    // ---------------- stage w1 -> w1g (bf16, k zero-padded 36->64), b1 -> b1s ----------------
    #pragma unroll
    for (int it = 0; it < 4; ++it) {
        const int idx = tid + it * 256;   // 0..1023 = n*8 + g
        const int n = idx >> 3, g = idx & 7;
        short8 pk;
        #pragma unroll
        for (int j = 0; j < 8; ++j) {
            const int k = g * 8 + j;
            pk[j] = (short)f2bf(k < 36 ? w1[n * 36 + k] : 0.0f);
        }
        *(short8*)(w1g + (g * 128 + n) * 8) = pk;
    }
    if (tid < 128) b1s[tid] = b1[tid];

    // ---------------- per-thread pooling of row (blk*256 + tid) ----------------
    const long row = (long)blockIdx.x * 256 + tid;
    const float* __restrict__ xr = x + row * NF;

    float f[169];
    #pragma unroll
    for (int i = 0; i < 42; ++i) {
        f4a v = *(const f4a*)(xr + i * 4);
        f[4*i+0] = v[0]; f[4*i+1] = v[1]; f[4*i+2] = v[2]; f[4*i+3] = v[3];
    }
    f[168] = xr[168];

    float pooled[36];
    #pragma unroll
    for (int i = 0; i < 6; ++i) {
        float cs[13];
        #pragma unroll
        for (int c = 0; c < 13; ++c) {
            float s = 0.0f;
            #pragma unroll
            for (int rr = 0; rr < 3; ++rr) {
                const int idx = (2 * i + rr) * 14 + c;   // compile-time
                if (idx < NF) s += f[idx];               // pad region = 0
            }
            cs[c] = s;
        }
        #pragma unroll
        for (int j = 0; j < 6; ++j) {
            const float s = cs[2*j] + cs[2*j+1] + cs[2*j+2];
            pooled[i * 6 + j] = fmaxf(s * (1.0f / 9.0f), 0.0f);
        }
    }

    // write pooled row to pool_g, k-groups of 8, zeros for k >= 36
    #pragma unroll
    for (int g = 0; g < 8; ++g) {
        short8 pk;
        #pragma unroll
        for (int j = 0; j < 8; ++j) {
            const int k = g * 8 + j;
            pk[j] = (k < 36) ? (short)f2bf(pooled[k]) : (short)0;
        }
        *(short8*)(pool_g + (g * 256 + tid) * 8) = pk;
    }
    __syncthreads();   // (1) pool_g complete

    // ---------------- A1 fragments (wave's 4 m-tiles) + w2/b2 fragments to registers ----------------
    short8 afrag[4][2];
    #pragma unroll
    for (int mt = 0; mt < 4; ++mt)
        #pragma unroll
        for (int ks = 0; ks < 2; ++ks) {
            const int g = ks * 4 + hi;
            afrag[mt][ks] = *(const short8*)(pool_g + (g * 256 + wid * 64 + mt * 16 + lr) * 8);
        }

    const int nOt = (wid < 3) ? 3 : 2;   // ot = wid + 4t, 11 total
    short8 wfrag[3][4];
    float  bias2[3];
    #pragma unroll
    for (int t = 0; t < 3; ++t) {
        const int ot = wid + 4 * t;
        const int o  = ot * 16 + lr;
        const bool valid = (t < nOt) && (o < NF);
        bias2[t] = valid ? b2[o] : 0.0f;
        #pragma unroll
        for (int ks = 0; ks < 4; ++ks) {
            short8 pk = {0, 0, 0, 0, 0, 0, 0, 0};
            if (valid) {
                const float* wp = w2 + o * NH + ks * 32 + hi * 8;
                #pragma unroll
                for (int j = 0; j < 8; ++j) pk[j] = (short)f2bf(wp[j]);
            }
            wfrag[t][ks] = pk;
        }
    }
    __syncthreads();   // (2) all a-frags read; pool region dead -> h_g may overwrite

    // ---------------- GEMM1: h = relu(pooled @ w1^T + b1), written to h_g ----------------
    short8 b1f[8][2];
    #pragma unroll
    for (int nt = 0; nt < 8; ++nt)
        #pragma unroll
        for (int ks = 0; ks < 2; ++ks) {
            const int g = ks * 4 + hi;
            b1f[nt][ks] = *(const short8*)(w1g + (g * 128 + nt * 16 + lr) * 8);
        }
    float bias1[8];
    #pragma unroll
    for (int nt = 0; nt < 8; ++nt) bias1[nt] = b1s[nt * 16 + lr];

    #pragma unroll
    for (int mt = 0; mt < 4; ++mt) {
        #pragma unroll
        for (int nt = 0; nt < 8; ++nt) {
            f32x4 c = {0.f, 0.f, 0.f, 0.f};
            c = MFMA(afrag[mt][0], b1f[nt][0], c);
            c = MFMA(afrag[mt][1], b1f[nt][1], c);
            const int g = 2 * nt + (lr >> 3);
            const int e = lr & 7;
            #pragma unroll
            for (int r = 0; r < 4; ++r) {
                const float v = fmaxf(c[r] + bias1[nt], 0.0f);
                const int rw = wid * 64 + mt * 16 + hi * 4 + r;
                h_g[(g * 256 + rw) * 8 + e] = (unsigned short)f2bf(v);
            }
        }
    }
    __syncthreads();   // (3) h_g complete; w1g dead -> stage usable

    // ---------------- GEMM2 (ot-split, w2 in regs) + staged coalesced stores ----------------
    const long blkRowBase = (long)blockIdx.x * 256;
    #pragma unroll 1
    for (int mt = 0; mt < 16; ++mt) {
        short8 a2[4];
        #pragma unroll
        for (int ks = 0; ks < 4; ++ks) {
            const int g = ks * 4 + hi;
            a2[ks] = *(const short8*)(h_g + (g * 256 + mt * 16 + lr) * 8);
        }
        f32x4 acc[3];
        #pragma unroll
        for (int t = 0; t < 3; ++t) {
            f32x4 c = {0.f, 0.f, 0.f, 0.f};
            #pragma unroll
            for (int ks = 0; ks < 4; ++ks)
                c = MFMA(a2[ks], wfrag[t][ks], c);
            acc[t] = c;
        }
        #pragma unroll
        for (int t = 0; t < 3; ++t) {
            const int ot = wid + 4 * t;
            const int o  = ot * 16 + lr;
            if (t < nOt && o < NF) {
                #pragma unroll
                for (int r = 0; r < 4; ++r)
                    stage[(hi * 4 + r) * NF + o] = acc[t][r] + bias2[t];
            }
        }
        __syncthreads();   // stage complete for this m-tile

        float* op = out + (blkRowBase + mt * 16) * NF;
        #pragma unroll
        for (int it = 0; it < 3; ++it) {
            const int i = tid + it * 256;
            if (i < 676) {                      // 16*169/4 float4s
                f32x4 v = *(const f32x4*)(stage + 4 * i);
                *(f32x4*)(op + 4 * i) = v;
            }
        }
        __syncthreads();   // stage consumed before next m-tile overwrites
    }
}

extern "C" void kernel_launch(void* const* d_in, const int* in_sizes, int n_in,
                              void* d_out, int out_size, void* d_ws, size_t ws_size,
                              hipStream_t stream) {
    const float* x  = (const float*)d_in[0];
    const float* w1 = (const float*)d_in[1];
    const float* b1 = (const float*)d_in[2];
    const float* w2 = (const float*)d_in[3];
    const float* b2 = (const float*)d_in[4];
    float* out = (float*)d_out;

    const int rows = in_sizes[0] / NF;      // 131072
    const int blocks = rows / 256;          // 512
    fused_v3<<<blocks, 256, 0, stream>>>(x, w1, b1, w2, b2, out);
}